// Round 9
// baseline (328.219 us; speedup 1.0000x reference)
//
#include <hip/hip_runtime.h>
#include <hip/hip_bf16.h>
#include <math.h>
#include <stdint.h>

#define HW2 (256*256)
#define HW1 (128*128)

typedef __attribute__((ext_vector_type(8))) short short8;
typedef __attribute__((ext_vector_type(4))) float floatx4;

__device__ __forceinline__ float b2f(ushort u) {
    union { unsigned int i; float f; } v; v.i = ((unsigned int)u) << 16; return v.f;
}
__device__ __forceinline__ ushort f2b(float f) {
    __hip_bfloat16 h = __float2bfloat16(f); return *(ushort*)&h;
}
__device__ __forceinline__ float fast_tanh(float x) {
    float cx = fminf(fmaxf(x, -15.f), 15.f);
    float t = __expf(2.f * cx);
    return (t - 1.f) / (t + 1.f);
}
// Async global->LDS 16B copy (fire-and-forget). Drained by __syncthreads().
__device__ __forceinline__ void gload_lds16(const void* g, void* l) {
    __builtin_amdgcn_global_load_lds(
        (__attribute__((address_space(1))) void*)(uintptr_t)g,
        (__attribute__((address_space(3))) void*)(unsigned)(uintptr_t)l,
        16, 0, 0);
}

// ===========================================================================
// Device bodies (shared by merged dispatches).
// ===========================================================================

__device__ __forceinline__
void repack_body(int gx, int role, int tid,
                 const float* __restrict__ wn_w1, const float* __restrict__ wn_w2,
                 const float* __restrict__ rb_w,
                 const float* __restrict__ dk_w1, const float* __restrict__ gk_w1,
                 const float* __restrict__ dk_w2, const float* __restrict__ gk_w2,
                 const float* __restrict__ wn_w3,
                 ushort* __restrict__ wt_wn1, ushort* __restrict__ wt_wn2,
                 ushort* __restrict__ wt_rb,
                 ushort* __restrict__ w1d, ushort* __restrict__ w1g,
                 ushort* __restrict__ w2d, ushort* __restrict__ w2g,
                 ushort* __restrict__ wt3) {
    int idx = gx * 256 + tid;
    if (role == 0) {
        if (idx >= 73728) return;
        int o = idx / 1152; int rem = idx - o * 1152;
        int ci = rem / 9;   int t = rem - ci * 9;
        wt_wn1[(((size_t)(ci >> 5) * 9 + t) * 64 + o) * 32 + (ci & 31)] = f2b(wn_w1[idx]);
    } else if (role <= 5) {
        if (idx >= 36864) return;
        const float* w = (role == 1) ? wn_w2 : rb_w + (size_t)(role - 2) * 36864;
        ushort* wt     = (role == 1) ? wt_wn2 : wt_rb + (size_t)(role - 2) * 36864;
        int o = idx / 576; int rem = idx - o * 576;
        int ci = rem / 9;  int t = rem - ci * 9;
        wt[(((size_t)(ci >> 5) * 9 + t) * 64 + o) * 32 + (ci & 31)] = f2b(w[idx]);
    } else if (role == 6) {
        if (idx >= 10240) return;
        if (idx < 4096)      w1d[idx] = f2b(dk_w1[idx]);
        else if (idx < 8192) w1g[idx - 4096] = f2b(gk_w1[idx - 4096]);
        else if (idx < 9216) { int i = idx - 8192; w2d[i] = (i >> 6) < 9 ? f2b(dk_w2[i]) : (ushort)0; }
        else                 { int i = idx - 9216; w2g[i] = (i >> 6) < 9 ? f2b(gk_w2[i]) : (ushort)0; }
    } else {
        if (idx >= 9216) return;
        int kc = idx / 512; int rem = idx - kc * 512;
        int n = rem >> 5, c = rem & 31;
        int cc = kc / 9, t = kc - cc * 9;
        wt3[idx] = (n == 0) ? f2b(wn_w3[(cc * 32 + c) * 9 + t]) : (ushort)0;
    }
}

__device__ __forceinline__
void to_chunked_body(int gx, int bc, int tid,
                     const float* __restrict__ in, ushort* __restrict__ outc,
                     int H, int W, int Cchunks) {
    int P = W + 2, Q = H + 2;
    int plane_px = P * Q;
    int idx = gx * 256 + tid;
    if (idx >= plane_px) return;
    int py = idx / P, px = idx - py * P;
    int b = bc / Cchunks, cc = bc - b * Cchunks;
    ushort* dst = outc + ((size_t)bc * plane_px + idx) * 32;
    short8* d8 = (short8*)dst;
    if (py == 0 || py == Q - 1 || px == 0 || px == P - 1) {
        short8 z = (short8){0, 0, 0, 0, 0, 0, 0, 0};
        d8[0] = z; d8[1] = z; d8[2] = z; d8[3] = z;
        return;
    }
    int y = py - 1, x = px - 1;
    const float* src = in + ((size_t)b * (Cchunks * 32) + cc * 32) * H * W
                          + (size_t)y * W + x;
    ushort tmp[32];
#pragma unroll
    for (int c = 0; c < 32; ++c)
        tmp[c] = f2b(src[(size_t)c * H * W]);
#pragma unroll
    for (int v = 0; v < 4; ++v) d8[v] = *(short8*)&tmp[v * 8];
}

__device__ __forceinline__
void hi4_body(int bx, int tid,
              const float* __restrict__ depth, const float* __restrict__ guide,
              ushort* __restrict__ outc) {
    int gid = bx * 256 + tid;
    int g   = gid & 63;
    int y   = (gid >> 6) & 255;
    int pl  = gid >> 14;
    const float* srcb = (pl < 4) ? depth : guide;
    int bc = pl & 3;
    int b = bc >> 1, cc = bc & 1;
    const float* src = srcb + ((size_t)b * 64 + cc * 32) * HW2 + (size_t)y * 256 + g * 4;
    ushort tmp[4][32];
#pragma unroll
    for (int c = 0; c < 32; ++c) {
        floatx4 v = *(const floatx4*)&src[(size_t)c * HW2];
        tmp[0][c] = f2b(v[0]); tmp[1][c] = f2b(v[1]);
        tmp[2][c] = f2b(v[2]); tmp[3][c] = f2b(v[3]);
    }
    ushort* dst = outc + ((size_t)pl * 258 * 258 + (size_t)(y + 1) * 258 + (g * 4 + 1)) * 32;
#pragma unroll
    for (int p = 0; p < 4; ++p) {
        short8* d8 = (short8*)(dst + (size_t)p * 32);
        d8[0] = *(short8*)&tmp[p][0];
        d8[1] = *(short8*)&tmp[p][8];
        d8[2] = *(short8*)&tmp[p][16];
        d8[3] = *(short8*)&tmp[p][24];
    }
}

__device__ __forceinline__
void zero_body(int gx, int region, int tid,
               ushort* __restrict__ buf256, ushort* __restrict__ buf128,
               ushort* __restrict__ bufhi) {
    int H = (region == 1) ? 128 : 256;
    int P = H + 2, Q = H + 2;
    ushort* buf = (region == 0) ? buf256 : (region == 1) ? buf128 : bufhi;
    int nb = 2 * P + 2 * H;
    int idx = gx * 256 + tid;
    if (idx >= nb * 8) return;
    int pl = idx / nb, r = idx - pl * nb;
    int py, px;
    if (r < P)          { py = 0;     px = r; }
    else if (r < 2 * P) { py = Q - 1; px = r - P; }
    else { int k = r - 2 * P; py = 1 + (k >> 1); px = (k & 1) ? P - 1 : 0; }
    ushort* dst = buf + ((size_t)pl * P * Q + (size_t)py * P + px) * 32;
    short8 z = (short8){0, 0, 0, 0, 0, 0, 0, 0};
    short8* d8 = (short8*)dst;
    d8[0] = z; d8[1] = z; d8[2] = z; d8[3] = z;
}

// ---- conv3x3 body. F32OUT: write fp32 to outf instead of bf16 to outc. ----
template<int NCHUNK, int ROWS, bool RELU, bool HAS_SKIP, bool CONCAT2, bool F32OUT>
__device__ __forceinline__
void conv_body(const ushort* __restrict__ inA, const ushort* __restrict__ inB,
               const ushort* __restrict__ wt, const float* __restrict__ bias,
               const ushort* __restrict__ skip, ushort* __restrict__ outc,
               float* __restrict__ outf,
               int H, int W, int b, int bx, int by, int tid) {
    const int P = W + 2;
    const size_t plane = (size_t)P * (H + 2) * 32;
    int wv = tid >> 6, lane = tid & 63, ml = lane & 15, q = lane >> 4;
    int x0 = bx * 16;
    int yb = by * (4 * ROWS) + wv * ROWS;

    floatx4 acc[ROWS][4];
#pragma unroll
    for (int r = 0; r < ROWS; ++r)
#pragma unroll
        for (int n = 0; n < 4; ++n) acc[r][n] = (floatx4){0.f, 0.f, 0.f, 0.f};

    for (int cc = 0; cc < NCHUNK; ++cc) {
        const ushort* base;
        if (CONCAT2) {
            constexpr int HC = NCHUNK / 2;
            if (cc < HC) base = inA + ((size_t)(b * HC + cc)) * plane;
            else         base = inB + ((size_t)(b * HC + cc - HC)) * plane;
        } else {
            base = inA + ((size_t)(b * NCHUNK + cc)) * plane;
        }
        const ushort* wb = wt + (size_t)cc * 18432;
#pragma unroll
        for (int dy = 0; dy < 3; ++dy) {
            short8 afr[3][ROWS], bfr[3][4];
#pragma unroll
            for (int dx = 0; dx < 3; ++dx) {
#pragma unroll
                for (int r = 0; r < ROWS; ++r)
                    afr[dx][r] = *(const short8*)&base[((size_t)(yb + r + dy) * P
                                                       + (x0 + ml + dx)) * 32 + q * 8];
#pragma unroll
                for (int n = 0; n < 4; ++n)
                    bfr[dx][n] = *(const short8*)&wb[(size_t)((dy * 3 + dx) * 64
                                                              + n * 16 + ml) * 32 + q * 8];
            }
#pragma unroll
            for (int dx = 0; dx < 3; ++dx)
#pragma unroll
                for (int r = 0; r < ROWS; ++r)
#pragma unroll
                    for (int n = 0; n < 4; ++n)
                        acc[r][n] = __builtin_amdgcn_mfma_f32_16x16x32_bf16(
                            afr[dx][r], bfr[dx][n], acc[r][n], 0, 0, 0);
        }
    }

#pragma unroll
    for (int r = 0; r < ROWS; ++r) {
        int y = yb + r;
#pragma unroll
        for (int n = 0; n < 4; ++n) {
            int ch = n * 16 + ml;
            int occ = ch >> 5, ocl = ch & 31;
            float bs = bias[ch];
            size_t pbase = ((size_t)(b * 2 + occ)) * plane + ((size_t)(y + 1) * P) * 32 + ocl;
#pragma unroll
            for (int e = 0; e < 4; ++e) {
                int x = x0 + q * 4 + e;
                float v = acc[r][n][e] + bs;
                if (RELU) v = fmaxf(v, 0.f);
                if (HAS_SKIP)
                    v += b2f(skip[((size_t)(b * 2 + occ)) * plane
                                  + ((size_t)(y + 1) * P + (x + 1)) * 32 + ocl]);
                if (F32OUT)
                    outf[pbase + (size_t)(x + 1) * 32] = v;
                else
                    outc[pbase + (size_t)(x + 1) * 32] = f2b(v);
            }
        }
    }
}

// ===========================================================================
// Dispatch 1: all prep work merged. grid = 3183 x 256.
// ===========================================================================
__global__ __launch_bounds__(256)
void prep_all(const float* __restrict__ depth, const float* __restrict__ guide,
              const float* __restrict__ inputs,
              const float* __restrict__ wn_w1, const float* __restrict__ wn_w2,
              const float* __restrict__ rb_w,
              const float* __restrict__ dk_w1, const float* __restrict__ gk_w1,
              const float* __restrict__ dk_w2, const float* __restrict__ gk_w2,
              const float* __restrict__ wn_w3,
              ushort* __restrict__ depth_c, ushort* __restrict__ inp_c,
              ushort* __restrict__ wt_wn1, ushort* __restrict__ wt_wn2,
              ushort* __restrict__ wt_rb,
              ushort* __restrict__ w1d, ushort* __restrict__ w1g,
              ushort* __restrict__ w2d, ushort* __restrict__ w2g,
              ushort* __restrict__ wt3,
              ushort* __restrict__ bufA, ushort* __restrict__ r0) {
    int bx = blockIdx.x, tid = threadIdx.x;
    if (bx < 512) {
        hi4_body(bx, tid, depth, guide, depth_c);
    } else if (bx < 780) {
        int v = bx - 512;
        to_chunked_body(v % 67, v / 67, tid, inputs, inp_c, 128, 128, 2);
    } else if (bx < 3084) {
        int v = bx - 780;
        repack_body(v % 288, v / 288, tid, wn_w1, wn_w2, rb_w, dk_w1, gk_w1,
                    dk_w2, gk_w2, wn_w3, wt_wn1, wt_wn2, wt_rb,
                    w1d, w1g, w2d, w2g, wt3);
    } else {
        int v = bx - 3084;
        zero_body(v % 33, v / 33, tid, bufA, r0, depth_c);
    }
}

// ===========================================================================
// Dispatch 2: conv1 (trunk) || rb0. grid (16,16,3).
// ===========================================================================
__global__ __launch_bounds__(256, 2)
void conv_pairA(const ushort* __restrict__ depth_c, const ushort* __restrict__ guide_c,
                const ushort* __restrict__ wt_wn1, const float* __restrict__ wn_b1,
                ushort* __restrict__ bufA,
                const ushort* __restrict__ inp_c, const ushort* __restrict__ wt_rb0,
                const float* __restrict__ rb_b0, ushort* __restrict__ r0) {
    int tid = threadIdx.x;
    if (blockIdx.z == 0) {
        int idx = blockIdx.y * 16 + blockIdx.x;
        int b = idx >> 7, rem = idx & 127;
        conv_body<2, 2, true, false, false, false>(inp_c, nullptr, wt_rb0, rb_b0, nullptr,
                                                   r0, nullptr, 128, 128, b, rem & 7, rem >> 3, tid);
    } else {
        conv_body<4, 4, true, false, true, false>(depth_c, guide_c, wt_wn1, wn_b1, nullptr,
                                                  bufA, nullptr, 256, 256, blockIdx.z - 1,
                                                  blockIdx.x, blockIdx.y, tid);
    }
}

// ===========================================================================
// Dispatch 3: conv2 (trunk) || rb1 (skip-add). grid (16,16,3).
// ===========================================================================
__global__ __launch_bounds__(256, 2)
void conv_pairB(const ushort* __restrict__ bufA,
                const ushort* __restrict__ wt_wn2, const float* __restrict__ wn_b2,
                ushort* __restrict__ bufB,
                const ushort* __restrict__ r0, const ushort* __restrict__ wt_rb1,
                const float* __restrict__ rb_b1, const ushort* __restrict__ inp_c,
                ushort* __restrict__ r1) {
    int tid = threadIdx.x;
    if (blockIdx.z == 0) {
        int idx = blockIdx.y * 16 + blockIdx.x;
        int b = idx >> 7, rem = idx & 127;
        conv_body<2, 2, false, true, false, false>(r0, nullptr, wt_rb1, rb_b1, inp_c,
                                                   r1, nullptr, 128, 128, b, rem & 7, rem >> 3, tid);
    } else {
        conv_body<2, 4, true, false, false, false>(bufA, nullptr, wt_wn2, wn_b2, nullptr,
                                                   bufB, nullptr, 256, 256, blockIdx.z - 1,
                                                   blockIdx.x, blockIdx.y, tid);
    }
}

// ===========================================================================
// Dispatch 4: fuse || rb2. grid = 2304 x 256.
// R9: hid single-buffered (branch d then branch g reuse the same per-wave
// region; same-wave in-order DS makes write->read->write->read safe).
// LDS 44032 -> 34816 B -> 3 blocks/CU (R7/R8 were LDS-capped at 2).
// ===========================================================================
__global__ __launch_bounds__(256, 2)
void fuse_rb2(const ushort* __restrict__ depth_c, const ushort* __restrict__ guide_c,
              const ushort* __restrict__ bufB,
              const ushort* __restrict__ wt3, const float* __restrict__ wn_b3,
              const ushort* __restrict__ w1d, const float* __restrict__ b1d,
              const ushort* __restrict__ w2d, const float* __restrict__ b2d,
              const ushort* __restrict__ w1g, const float* __restrict__ b1g,
              const ushort* __restrict__ w2g, const float* __restrict__ b2g,
              const float* __restrict__ aff, float* __restrict__ fuse_out,
              const ushort* __restrict__ r1, const ushort* __restrict__ wt_rb2,
              const float* __restrict__ rb_b2, ushort* __restrict__ r0) {
    int tid = threadIdx.x;
    if (blockIdx.x < 256) {
        int idx = blockIdx.x;
        int b = idx >> 7, rem = idx & 127;
        conv_body<2, 2, true, false, false, false>(r1, nullptr, wt_rb2, rb_b2, nullptr,
                                                   r0, nullptr, 128, 128, b, rem & 7, rem >> 3, tid);
        return;
    }
    int bxl = blockIdx.x - 256;

    __shared__ __align__(16) ushort stage[12672];   // 25344 B taps
    __shared__ __align__(16) ushort hid[4][16 * 72]; // 9216 B (single branch buf)
    __shared__ float wmv[4][16];

    int wv = tid >> 6, lane = tid & 63, ml = lane & 15, q = lane >> 4;
    int p0 = bxl * 64 + wv * 16;
    int b = p0 >> 16, rem0 = p0 & 65535;
    const size_t plane = (size_t)258 * 258 * 32;

    int rem = rem0 + ml;
    int y = rem >> 8, x = rem & 255;
    size_t poff = ((size_t)(y + 1) * 258 + (x + 1)) * 32;

    int pb  = bxl * 64;
    int y0  = (pb & 65535) >> 8;
    int x0b = pb & 255;

    short8 afr[2][2];
#pragma unroll
    for (int kc = 0; kc < 2; ++kc) {
        afr[0][kc] = *(const short8*)&depth_c[(size_t)(b * 2 + kc) * plane + poff + q * 8];
        afr[1][kc] = *(const short8*)&guide_c[(size_t)(b * 2 + kc) * plane + poff + q * 8];
    }

    const ushort* bbase = bufB + (size_t)(b * 2) * plane;
#pragma unroll
    for (int i = 0; i < 7; ++i) {
        int wofs = i * 4096 + (wv << 10);
        int ofs  = wofs + (lane << 4);
        if (ofs < 25344) {
            int seg = ofs / 4224;
            int within = ofs - seg * 4224;
            int cc2 = seg / 3, r = seg - cc2 * 3;
            const ushort* gsrc = bbase + (size_t)cc2 * plane
                               + ((size_t)(y0 + r) * 258 + x0b) * 32 + (within >> 1);
            gload_lds16(gsrc, (char*)stage + wofs);
        }
    }
    __syncthreads();

    floatx4 acc[2][4];
#pragma unroll
    for (int br = 0; br < 2; ++br)
#pragma unroll
        for (int nt = 0; nt < 4; ++nt) acc[br][nt] = (floatx4){0.f, 0.f, 0.f, 0.f};
#pragma unroll
    for (int nt = 0; nt < 4; ++nt)
#pragma unroll
        for (int kc = 0; kc < 2; ++kc) {
            short8 bD = *(const short8*)&w1d[(size_t)((nt * 16 + ml) * 64 + kc * 32 + q * 8)];
            short8 bG = *(const short8*)&w1g[(size_t)((nt * 16 + ml) * 64 + kc * 32 + q * 8)];
            acc[0][nt] = __builtin_amdgcn_mfma_f32_16x16x32_bf16(afr[0][kc], bD, acc[0][nt], 0, 0, 0);
            acc[1][nt] = __builtin_amdgcn_mfma_f32_16x16x32_bf16(afr[1][kc], bG, acc[1][nt], 0, 0, 0);
        }

    int colb = (wv << 4) + ml;
    floatx4 dw[4];
#pragma unroll
    for (int u = 0; u < 4; ++u) dw[u] = (floatx4){0.f, 0.f, 0.f, 0.f};
#pragma unroll
    for (int t = 0; t < 9; ++t) {
        int dy2 = t / 3, dx2 = t - 3 * dy2;
        short8 a0 = *(const short8*)&stage[(size_t)(dy2 * 66 + colb + dx2) * 32 + q * 8];
        short8 b3 = *(const short8*)&wt3[(size_t)(t * 512 + ml * 32 + q * 8)];
        dw[t & 3] = __builtin_amdgcn_mfma_f32_16x16x32_bf16(a0, b3, dw[t & 3], 0, 0, 0);
    }
#pragma unroll
    for (int t = 0; t < 9; ++t) {
        int dy2 = t / 3, dx2 = t - 3 * dy2;
        short8 a1 = *(const short8*)&stage[(size_t)((3 + dy2) * 66 + colb + dx2) * 32 + q * 8];
        short8 b3 = *(const short8*)&wt3[(size_t)((9 + t) * 512 + ml * 32 + q * 8)];
        dw[t & 3] = __builtin_amdgcn_mfma_f32_16x16x32_bf16(a1, b3, dw[t & 3], 0, 0, 0);
    }
    floatx4 dwm = (dw[0] + dw[1]) + (dw[2] + dw[3]);
    if (ml == 0) {
#pragma unroll
        for (int e = 0; e < 4; ++e) wmv[wv][q * 4 + e] = dwm[e];
    }

    // ---- branches d, g sequentially through the SAME hid buffer ----------
    floatx4 d2v[2];
#pragma unroll
    for (int br = 0; br < 2; ++br) {
        const float*  b1 = br ? b1g : b1d;
        const ushort* w2 = br ? w2g : w2d;
        ushort* h = hid[wv];
#pragma unroll
        for (int nt = 0; nt < 4; ++nt) {
            float bs = b1[nt * 16 + ml];
#pragma unroll
            for (int e = 0; e < 4; ++e) {
                float v = acc[br][nt][e] + bs;
                v = fmaxf(v, 0.f);
                h[(q * 4 + e) * 72 + nt * 16 + ml] = f2b(v);
            }
        }
        floatx4 d2 = (floatx4){0.f, 0.f, 0.f, 0.f};
#pragma unroll
        for (int kc = 0; kc < 2; ++kc) {
            short8 a2 = *(const short8*)&w2[(size_t)(ml * 64 + kc * 32 + q * 8)];
            short8 hf = *(const short8*)&h[ml * 72 + kc * 32 + q * 8];
            d2 = __builtin_amdgcn_mfma_f32_16x16x32_bf16(a2, hf, d2, 0, 0, 0);
        }
        d2v[br] = d2;
    }

    float wm = wmv[wv][ml] + wn_b3[0];

    float sm[2][4];
#pragma unroll
    for (int br = 0; br < 2; ++br) {
        const float* b2 = br ? b2g : b2d;
        float lg[4];
#pragma unroll
        for (int e = 0; e < 4; ++e) {
            int j = q * 4 + e;
            lg[e] = (j < 9) ? (d2v[br][e] + b2[j]) : -1e30f;
        }
        float m = fmaxf(fmaxf(lg[0], lg[1]), fmaxf(lg[2], lg[3]));
        m = fmaxf(m, __shfl_xor(m, 16));
        m = fmaxf(m, __shfl_xor(m, 32));
        float s = 0.f;
#pragma unroll
        for (int e = 0; e < 4; ++e) { lg[e] = __expf(lg[e] - m); s += lg[e]; }
        s += __shfl_xor(s, 16);
        s += __shfl_xor(s, 32);
        float inv = 1.f / s;
#pragma unroll
        for (int e = 0; e < 4; ++e) sm[br][e] = lg[e] * inv;
    }

    float inv_av = 1.f / (aff[0] + 1e-8f);
    float f[4];
    float s = 0.f;
#pragma unroll
    for (int e = 0; e < 4; ++e) {
        float v = wm * sm[0][e] + (1.f - wm) * sm[1][e];
        v = fast_tanh(v) * inv_av;
        f[e] = v;
        s += fabsf(v);
    }
    s += __shfl_xor(s, 16);
    s += __shfl_xor(s, 32);
    float ksum = s + 1e-4f;
    if (ksum < 1.f) ksum = 1.f;
    float invk = 1.f / ksum;
#pragma unroll
    for (int e = 0; e < 4; ++e) {
        int j = q * 4 + e;
        if (j < 9)
            fuse_out[((size_t)b * 9 + j) * HW2 + rem0 + ml] = f[e] * invk;
    }
}

// ===========================================================================
// Dispatch 5: rb3 standalone, fp32 output into the dead bufA region.
// ===========================================================================
__global__ __launch_bounds__(256, 2)
void conv_single(const ushort* __restrict__ inA, const ushort* __restrict__ wt,
                 const float* __restrict__ bias, const ushort* __restrict__ skip,
                 float* __restrict__ outf) {
    conv_body<2, 2, false, true, false, true>(inA, nullptr, wt, bias, skip, nullptr,
                                              outf, 128, 128, blockIdx.z,
                                              blockIdx.x, blockIdx.y, threadIdx.x);
}

// ===========================================================================
// Dispatch 6: fused bilinear-upsample + 9-tap dilated gather (fp32 r2).
// ===========================================================================
__global__ __launch_bounds__(256)
void fuse_apply_up(const float* __restrict__ fuse, const float* __restrict__ r2f,
                   float* __restrict__ out) {
    int p = blockIdx.x * 256 + threadIdx.x;
    int pl = blockIdx.y;
    int b = pl >> 1, cc = pl & 1;
    int y = p >> 8, x = p & 255;

    int my = y >> 1, mx = x >> 1;
    float wyA = (y & 1) ? 0.75f : 0.25f;  float wyB = 1.f - wyA;
    float wxA = (x & 1) ? 0.75f : 0.25f;  float wxB = 1.f - wxA;
    int R0y = my + ((y & 1) ? 0 : -1) - 1;
    int R0x = mx + ((x & 1) ? 0 : -1) - 1;

    const float* f = fuse + (size_t)b * 9 * HW2 + p;
    float coef[4][4];
#pragma unroll
    for (int k = 0; k < 4; ++k)
#pragma unroll
        for (int l = 0; l < 4; ++l) coef[k][l] = 0.f;

#pragma unroll
    for (int ty = 0; ty < 3; ++ty) {
        int yp = y + (ty - 1) * 2;
        if (yp < 0 || yp > 255) continue;
#pragma unroll
        for (int tx = 0; tx < 3; ++tx) {
            int xp = x + (tx - 1) * 2;
            if (xp < 0 || xp > 255) continue;
            float fv = f[(size_t)(ty * 3 + tx) * HW2];
            coef[ty][tx]         += fv * wyA * wxA;
            coef[ty][tx + 1]     += fv * wyA * wxB;
            coef[ty + 1][tx]     += fv * wyB * wxA;
            coef[ty + 1][tx + 1] += fv * wyB * wxB;
        }
    }

    const float* base = r2f + (size_t)pl * 130 * 130 * 32;
    float acc[32];
#pragma unroll
    for (int c = 0; c < 32; ++c) acc[c] = 0.f;
#pragma unroll
    for (int k = 0; k < 4; ++k) {
        int ry = R0y + k; ry = ry < 0 ? 0 : (ry > 127 ? 127 : ry);
#pragma unroll
        for (int l = 0; l < 4; ++l) {
            int rx = R0x + l; rx = rx < 0 ? 0 : (rx > 127 ? 127 : rx);
            float cf = coef[k][l];
            const float* u = base + ((size_t)(ry + 1) * 130 + (rx + 1)) * 32;
#pragma unroll
            for (int c = 0; c < 32; ++c) acc[c] = fmaf(cf, u[c], acc[c]);
        }
    }
    float* ob = out + ((size_t)(b * 64 + cc * 32)) * HW2 + p;
#pragma unroll
    for (int c = 0; c < 32; ++c) ob[(size_t)c * HW2] = acc[c];
}

// ---------------------------------------------------------------------------
extern "C" void kernel_launch(void* const* d_in, const int* in_sizes, int n_in,
                              void* d_out, int out_size, void* d_ws, size_t ws_size,
                              hipStream_t stream) {
    const float* depth  = (const float*)d_in[0];
    const float* guide  = (const float*)d_in[1];
    const float* inputs = (const float*)d_in[2];
    const float* dk_w1  = (const float*)d_in[3];
    const float* dk_b1  = (const float*)d_in[4];
    const float* dk_w2  = (const float*)d_in[5];
    const float* dk_b2  = (const float*)d_in[6];
    const float* gk_w1  = (const float*)d_in[7];
    const float* gk_b1  = (const float*)d_in[8];
    const float* gk_w2  = (const float*)d_in[9];
    const float* gk_b2  = (const float*)d_in[10];
    const float* wn_w1  = (const float*)d_in[11];
    const float* wn_b1  = (const float*)d_in[12];
    const float* wn_w2  = (const float*)d_in[13];
    const float* wn_b2  = (const float*)d_in[14];
    const float* wn_w3  = (const float*)d_in[15];
    const float* wn_b3  = (const float*)d_in[16];
    const float* rb_w   = (const float*)d_in[17];
    const float* rb_b   = (const float*)d_in[18];
    const float* aff    = (const float*)d_in[19];
    float* out = (float*)d_out;

    float* ws = (float*)d_ws;
    size_t off = 0;
    const size_t CH256 = 4260096;
    const size_t CH128 = 1081600;
    ushort* depth_c = (ushort*)(ws + off); off += CH256;
    ushort* guide_c = (ushort*)(ws + off); off += CH256;
    ushort* bufA    = (ushort*)(ws + off); off += CH256;
    ushort* bufB    = (ushort*)(ws + off); off += CH256;
    ushort* inp_c   = (ushort*)(ws + off); off += CH128;
    ushort* r0      = (ushort*)(ws + off); off += CH128;
    ushort* r1      = (ushort*)(ws + off); off += CH128;
    ushort* r2      = (ushort*)(ws + off); off += CH128;  // unused (kept for layout)
    float* fuse     = ws + off; off += 1179648;
    ushort* wt_wn1  = (ushort*)(ws + off); off += 36864;
    ushort* wt_wn2  = (ushort*)(ws + off); off += 18432;
    ushort* wt_rb   = (ushort*)(ws + off); off += 73728;
    ushort* w1d_b   = (ushort*)(ws + off); off += 2048;
    ushort* w1g_b   = (ushort*)(ws + off); off += 2048;
    ushort* w2d_b   = (ushort*)(ws + off); off += 512;
    ushort* w2g_b   = (ushort*)(ws + off); off += 512;
    ushort* wt3_b   = (ushort*)(ws + off); off += 4608;

    // rb3 fp32 output lives in bufA (dead after conv_pairB): 4 planes x
    // 130*130*32 floats = 2,163,200 floats < CH256.
    float* r2f = (float*)bufA;

    // D1: all prep
    prep_all<<<3183, 256, 0, stream>>>(
        depth, guide, inputs, wn_w1, wn_w2, rb_w, dk_w1, gk_w1, dk_w2, gk_w2,
        wn_w3, depth_c, inp_c, wt_wn1, wt_wn2, wt_rb,
        w1d_b, w1g_b, w2d_b, w2g_b, wt3_b, bufA, r0);

    // D2: conv1 || rb0
    conv_pairA<<<dim3(16, 16, 3), 256, 0, stream>>>(
        depth_c, guide_c, wt_wn1, wn_b1, bufA,
        inp_c, wt_rb + 0 * 36864, rb_b + 0 * 64, r0);

    // D3: conv2 || rb1
    conv_pairB<<<dim3(16, 16, 3), 256, 0, stream>>>(
        bufA, wt_wn2, wn_b2, bufB,
        r0, wt_rb + 1 * 36864, rb_b + 1 * 64, inp_c, r1);

    // D4: fuse || rb2
    fuse_rb2<<<2304, 256, 0, stream>>>(
        depth_c, guide_c, bufB, wt3_b, wn_b3,
        w1d_b, dk_b1, w2d_b, dk_b2, w1g_b, gk_b1, w2g_b, gk_b2,
        aff, fuse,
        r1, wt_rb + 2 * 36864, rb_b + 2 * 64, r0);

    // D5: rb3 (fp32 out into bufA region)
    conv_single<<<dim3(8, 16, 2), 256, 0, stream>>>(
        r0, wt_rb + 3 * 36864, rb_b + 3 * 64, r1, r2f);

    // D6: fused upsample + gather (fp32 r2)
    fuse_apply_up<<<dim3(256, 4), 256, 0, stream>>>(fuse, r2f, out);
}

// Round 10
// 298.461 us; speedup vs baseline: 1.0997x; 1.0997x over previous
//
#include <hip/hip_runtime.h>
#include <hip/hip_bf16.h>
#include <math.h>
#include <stdint.h>

#define HW2 (256*256)
#define HW1 (128*128)

typedef __attribute__((ext_vector_type(8))) short short8;
typedef __attribute__((ext_vector_type(4))) float floatx4;

__device__ __forceinline__ float b2f(ushort u) {
    union { unsigned int i; float f; } v; v.i = ((unsigned int)u) << 16; return v.f;
}
__device__ __forceinline__ ushort f2b(float f) {
    __hip_bfloat16 h = __float2bfloat16(f); return *(ushort*)&h;
}
__device__ __forceinline__ float fast_tanh(float x) {
    float cx = fminf(fmaxf(x, -15.f), 15.f);
    float t = __expf(2.f * cx);
    return (t - 1.f) / (t + 1.f);
}
// Async global->LDS 16B copy (fire-and-forget). Drained by __syncthreads().
__device__ __forceinline__ void gload_lds16(const void* g, void* l) {
    __builtin_amdgcn_global_load_lds(
        (__attribute__((address_space(1))) void*)(uintptr_t)g,
        (__attribute__((address_space(3))) void*)(unsigned)(uintptr_t)l,
        16, 0, 0);
}

// ===========================================================================
// Device bodies (shared by merged dispatches).
// ===========================================================================

__device__ __forceinline__
void repack_body(int gx, int role, int tid,
                 const float* __restrict__ wn_w1, const float* __restrict__ wn_w2,
                 const float* __restrict__ rb_w,
                 const float* __restrict__ dk_w1, const float* __restrict__ gk_w1,
                 const float* __restrict__ dk_w2, const float* __restrict__ gk_w2,
                 const float* __restrict__ wn_w3,
                 ushort* __restrict__ wt_wn1, ushort* __restrict__ wt_wn2,
                 ushort* __restrict__ wt_rb,
                 ushort* __restrict__ w1d, ushort* __restrict__ w1g,
                 ushort* __restrict__ w2d, ushort* __restrict__ w2g,
                 ushort* __restrict__ wt3) {
    int idx = gx * 256 + tid;
    if (role == 0) {
        if (idx >= 73728) return;
        int o = idx / 1152; int rem = idx - o * 1152;
        int ci = rem / 9;   int t = rem - ci * 9;
        wt_wn1[(((size_t)(ci >> 5) * 9 + t) * 64 + o) * 32 + (ci & 31)] = f2b(wn_w1[idx]);
    } else if (role <= 5) {
        if (idx >= 36864) return;
        const float* w = (role == 1) ? wn_w2 : rb_w + (size_t)(role - 2) * 36864;
        ushort* wt     = (role == 1) ? wt_wn2 : wt_rb + (size_t)(role - 2) * 36864;
        int o = idx / 576; int rem = idx - o * 576;
        int ci = rem / 9;  int t = rem - ci * 9;
        wt[(((size_t)(ci >> 5) * 9 + t) * 64 + o) * 32 + (ci & 31)] = f2b(w[idx]);
    } else if (role == 6) {
        if (idx >= 10240) return;
        if (idx < 4096)      w1d[idx] = f2b(dk_w1[idx]);
        else if (idx < 8192) w1g[idx - 4096] = f2b(gk_w1[idx - 4096]);
        else if (idx < 9216) { int i = idx - 8192; w2d[i] = (i >> 6) < 9 ? f2b(dk_w2[i]) : (ushort)0; }
        else                 { int i = idx - 9216; w2g[i] = (i >> 6) < 9 ? f2b(gk_w2[i]) : (ushort)0; }
    } else {
        if (idx >= 9216) return;
        int kc = idx / 512; int rem = idx - kc * 512;
        int n = rem >> 5, c = rem & 31;
        int cc = kc / 9, t = kc - cc * 9;
        wt3[idx] = (n == 0) ? f2b(wn_w3[(cc * 32 + c) * 9 + t]) : (ushort)0;
    }
}

__device__ __forceinline__
void to_chunked_body(int gx, int bc, int tid,
                     const float* __restrict__ in, ushort* __restrict__ outc,
                     int H, int W, int Cchunks) {
    int P = W + 2, Q = H + 2;
    int plane_px = P * Q;
    int idx = gx * 256 + tid;
    if (idx >= plane_px) return;
    int py = idx / P, px = idx - py * P;
    int b = bc / Cchunks, cc = bc - b * Cchunks;
    ushort* dst = outc + ((size_t)bc * plane_px + idx) * 32;
    short8* d8 = (short8*)dst;
    if (py == 0 || py == Q - 1 || px == 0 || px == P - 1) {
        short8 z = (short8){0, 0, 0, 0, 0, 0, 0, 0};
        d8[0] = z; d8[1] = z; d8[2] = z; d8[3] = z;
        return;
    }
    int y = py - 1, x = px - 1;
    const float* src = in + ((size_t)b * (Cchunks * 32) + cc * 32) * H * W
                          + (size_t)y * W + x;
    ushort tmp[32];
#pragma unroll
    for (int c = 0; c < 32; ++c)
        tmp[c] = f2b(src[(size_t)c * H * W]);
#pragma unroll
    for (int v = 0; v < 4; ++v) d8[v] = *(short8*)&tmp[v * 8];
}

__device__ __forceinline__
void hi4_body(int bx, int tid,
              const float* __restrict__ depth, const float* __restrict__ guide,
              ushort* __restrict__ outc) {
    int gid = bx * 256 + tid;
    int g   = gid & 63;
    int y   = (gid >> 6) & 255;
    int pl  = gid >> 14;
    const float* srcb = (pl < 4) ? depth : guide;
    int bc = pl & 3;
    int b = bc >> 1, cc = bc & 1;
    const float* src = srcb + ((size_t)b * 64 + cc * 32) * HW2 + (size_t)y * 256 + g * 4;
    ushort tmp[4][32];
#pragma unroll
    for (int c = 0; c < 32; ++c) {
        floatx4 v = *(const floatx4*)&src[(size_t)c * HW2];
        tmp[0][c] = f2b(v[0]); tmp[1][c] = f2b(v[1]);
        tmp[2][c] = f2b(v[2]); tmp[3][c] = f2b(v[3]);
    }
    ushort* dst = outc + ((size_t)pl * 258 * 258 + (size_t)(y + 1) * 258 + (g * 4 + 1)) * 32;
#pragma unroll
    for (int p = 0; p < 4; ++p) {
        short8* d8 = (short8*)(dst + (size_t)p * 32);
        d8[0] = *(short8*)&tmp[p][0];
        d8[1] = *(short8*)&tmp[p][8];
        d8[2] = *(short8*)&tmp[p][16];
        d8[3] = *(short8*)&tmp[p][24];
    }
}

__device__ __forceinline__
void zero_body(int gx, int region, int tid,
               ushort* __restrict__ buf256, ushort* __restrict__ buf128,
               ushort* __restrict__ bufhi) {
    int H = (region == 1) ? 128 : 256;
    int P = H + 2, Q = H + 2;
    ushort* buf = (region == 0) ? buf256 : (region == 1) ? buf128 : bufhi;
    int nb = 2 * P + 2 * H;
    int idx = gx * 256 + tid;
    if (idx >= nb * 8) return;
    int pl = idx / nb, r = idx - pl * nb;
    int py, px;
    if (r < P)          { py = 0;     px = r; }
    else if (r < 2 * P) { py = Q - 1; px = r - P; }
    else { int k = r - 2 * P; py = 1 + (k >> 1); px = (k & 1) ? P - 1 : 0; }
    ushort* dst = buf + ((size_t)pl * P * Q + (size_t)py * P + px) * 32;
    short8 z = (short8){0, 0, 0, 0, 0, 0, 0, 0};
    short8* d8 = (short8*)dst;
    d8[0] = z; d8[1] = z; d8[2] = z; d8[3] = z;
}

// ---- conv3x3 body (tap-triple batching) ----
template<int NCHUNK, int ROWS, bool RELU, bool HAS_SKIP, bool CONCAT2>
__device__ __forceinline__
void conv_body(const ushort* __restrict__ inA, const ushort* __restrict__ inB,
               const ushort* __restrict__ wt, const float* __restrict__ bias,
               const ushort* __restrict__ skip, ushort* __restrict__ outc,
               int H, int W, int b, int bx, int by, int tid) {
    const int P = W + 2;
    const size_t plane = (size_t)P * (H + 2) * 32;
    int wv = tid >> 6, lane = tid & 63, ml = lane & 15, q = lane >> 4;
    int x0 = bx * 16;
    int yb = by * (4 * ROWS) + wv * ROWS;

    floatx4 acc[ROWS][4];
#pragma unroll
    for (int r = 0; r < ROWS; ++r)
#pragma unroll
        for (int n = 0; n < 4; ++n) acc[r][n] = (floatx4){0.f, 0.f, 0.f, 0.f};

    for (int cc = 0; cc < NCHUNK; ++cc) {
        const ushort* base;
        if (CONCAT2) {
            constexpr int HC = NCHUNK / 2;
            if (cc < HC) base = inA + ((size_t)(b * HC + cc)) * plane;
            else         base = inB + ((size_t)(b * HC + cc - HC)) * plane;
        } else {
            base = inA + ((size_t)(b * NCHUNK + cc)) * plane;
        }
        const ushort* wb = wt + (size_t)cc * 18432;
#pragma unroll
        for (int dy = 0; dy < 3; ++dy) {
            short8 afr[3][ROWS], bfr[3][4];
#pragma unroll
            for (int dx = 0; dx < 3; ++dx) {
#pragma unroll
                for (int r = 0; r < ROWS; ++r)
                    afr[dx][r] = *(const short8*)&base[((size_t)(yb + r + dy) * P
                                                       + (x0 + ml + dx)) * 32 + q * 8];
#pragma unroll
                for (int n = 0; n < 4; ++n)
                    bfr[dx][n] = *(const short8*)&wb[(size_t)((dy * 3 + dx) * 64
                                                              + n * 16 + ml) * 32 + q * 8];
            }
#pragma unroll
            for (int dx = 0; dx < 3; ++dx)
#pragma unroll
                for (int r = 0; r < ROWS; ++r)
#pragma unroll
                    for (int n = 0; n < 4; ++n)
                        acc[r][n] = __builtin_amdgcn_mfma_f32_16x16x32_bf16(
                            afr[dx][r], bfr[dx][n], acc[r][n], 0, 0, 0);
        }
    }

#pragma unroll
    for (int r = 0; r < ROWS; ++r) {
        int y = yb + r;
#pragma unroll
        for (int n = 0; n < 4; ++n) {
            int ch = n * 16 + ml;
            int occ = ch >> 5, ocl = ch & 31;
            float bs = bias[ch];
            size_t pbase = ((size_t)(b * 2 + occ)) * plane + ((size_t)(y + 1) * P) * 32 + ocl;
#pragma unroll
            for (int e = 0; e < 4; ++e) {
                int x = x0 + q * 4 + e;
                float v = acc[r][n][e] + bs;
                if (RELU) v = fmaxf(v, 0.f);
                if (HAS_SKIP)
                    v += b2f(skip[((size_t)(b * 2 + occ)) * plane
                                  + ((size_t)(y + 1) * P + (x + 1)) * 32 + ocl]);
                outc[pbase + (size_t)(x + 1) * 32] = f2b(v);
            }
        }
    }
}

// ===========================================================================
// Dispatch 1: all prep work merged. grid = 3183 x 256.
// ===========================================================================
__global__ __launch_bounds__(256)
void prep_all(const float* __restrict__ depth, const float* __restrict__ guide,
              const float* __restrict__ inputs,
              const float* __restrict__ wn_w1, const float* __restrict__ wn_w2,
              const float* __restrict__ rb_w,
              const float* __restrict__ dk_w1, const float* __restrict__ gk_w1,
              const float* __restrict__ dk_w2, const float* __restrict__ gk_w2,
              const float* __restrict__ wn_w3,
              ushort* __restrict__ depth_c, ushort* __restrict__ inp_c,
              ushort* __restrict__ wt_wn1, ushort* __restrict__ wt_wn2,
              ushort* __restrict__ wt_rb,
              ushort* __restrict__ w1d, ushort* __restrict__ w1g,
              ushort* __restrict__ w2d, ushort* __restrict__ w2g,
              ushort* __restrict__ wt3,
              ushort* __restrict__ bufA, ushort* __restrict__ r0) {
    int bx = blockIdx.x, tid = threadIdx.x;
    if (bx < 512) {
        hi4_body(bx, tid, depth, guide, depth_c);
    } else if (bx < 780) {
        int v = bx - 512;
        to_chunked_body(v % 67, v / 67, tid, inputs, inp_c, 128, 128, 2);
    } else if (bx < 3084) {
        int v = bx - 780;
        repack_body(v % 288, v / 288, tid, wn_w1, wn_w2, rb_w, dk_w1, gk_w1,
                    dk_w2, gk_w2, wn_w3, wt_wn1, wt_wn2, wt_rb,
                    w1d, w1g, w2d, w2g, wt3);
    } else {
        int v = bx - 3084;
        zero_body(v % 33, v / 33, tid, bufA, r0, depth_c);
    }
}

// ===========================================================================
// Dispatch 2: conv1 (trunk) || rb0. grid (16,16,3).
// ===========================================================================
__global__ __launch_bounds__(256, 2)
void conv_pairA(const ushort* __restrict__ depth_c, const ushort* __restrict__ guide_c,
                const ushort* __restrict__ wt_wn1, const float* __restrict__ wn_b1,
                ushort* __restrict__ bufA,
                const ushort* __restrict__ inp_c, const ushort* __restrict__ wt_rb0,
                const float* __restrict__ rb_b0, ushort* __restrict__ r0) {
    int tid = threadIdx.x;
    if (blockIdx.z == 0) {
        int idx = blockIdx.y * 16 + blockIdx.x;
        int b = idx >> 7, rem = idx & 127;
        conv_body<2, 2, true, false, false>(inp_c, nullptr, wt_rb0, rb_b0, nullptr,
                                            r0, 128, 128, b, rem & 7, rem >> 3, tid);
    } else {
        conv_body<4, 4, true, false, true>(depth_c, guide_c, wt_wn1, wn_b1, nullptr,
                                           bufA, 256, 256, blockIdx.z - 1,
                                           blockIdx.x, blockIdx.y, tid);
    }
}

// ===========================================================================
// Dispatch 3: conv2 (trunk) || rb1 (skip-add). grid (16,16,3).
// ===========================================================================
__global__ __launch_bounds__(256, 2)
void conv_pairB(const ushort* __restrict__ bufA,
                const ushort* __restrict__ wt_wn2, const float* __restrict__ wn_b2,
                ushort* __restrict__ bufB,
                const ushort* __restrict__ r0, const ushort* __restrict__ wt_rb1,
                const float* __restrict__ rb_b1, const ushort* __restrict__ inp_c,
                ushort* __restrict__ r1) {
    int tid = threadIdx.x;
    if (blockIdx.z == 0) {
        int idx = blockIdx.y * 16 + blockIdx.x;
        int b = idx >> 7, rem = idx & 127;
        conv_body<2, 2, false, true, false>(r0, nullptr, wt_rb1, rb_b1, inp_c,
                                            r1, 128, 128, b, rem & 7, rem >> 3, tid);
    } else {
        conv_body<2, 4, true, false, false>(bufA, nullptr, wt_wn2, wn_b2, nullptr,
                                            bufB, 256, 256, blockIdx.z - 1,
                                            blockIdx.x, blockIdx.y, tid);
    }
}

// ===========================================================================
// Dispatch 4: fuse || rb2. grid = 2304 x 256. (R8 version, dual hid buffer.)
// ===========================================================================
__global__ __launch_bounds__(256, 2)
void fuse_rb2(const ushort* __restrict__ depth_c, const ushort* __restrict__ guide_c,
              const ushort* __restrict__ bufB,
              const ushort* __restrict__ wt3, const float* __restrict__ wn_b3,
              const ushort* __restrict__ w1d, const float* __restrict__ b1d,
              const ushort* __restrict__ w2d, const float* __restrict__ b2d,
              const ushort* __restrict__ w1g, const float* __restrict__ b1g,
              const ushort* __restrict__ w2g, const float* __restrict__ b2g,
              const float* __restrict__ aff, float* __restrict__ fuse_out,
              const ushort* __restrict__ r1, const ushort* __restrict__ wt_rb2,
              const float* __restrict__ rb_b2, ushort* __restrict__ r0) {
    int tid = threadIdx.x;
    if (blockIdx.x < 256) {
        int idx = blockIdx.x;
        int b = idx >> 7, rem = idx & 127;
        conv_body<2, 2, true, false, false>(r1, nullptr, wt_rb2, rb_b2, nullptr,
                                            r0, 128, 128, b, rem & 7, rem >> 3, tid);
        return;
    }
    int bxl = blockIdx.x - 256;

    __shared__ __align__(16) ushort stage[12672];
    __shared__ __align__(16) ushort hid[2][4][16 * 72];
    __shared__ float wmv[4][16];

    int wv = tid >> 6, lane = tid & 63, ml = lane & 15, q = lane >> 4;
    int p0 = bxl * 64 + wv * 16;
    int b = p0 >> 16, rem0 = p0 & 65535;
    const size_t plane = (size_t)258 * 258 * 32;

    int rem = rem0 + ml;
    int y = rem >> 8, x = rem & 255;
    size_t poff = ((size_t)(y + 1) * 258 + (x + 1)) * 32;

    int pb  = bxl * 64;
    int y0  = (pb & 65535) >> 8;
    int x0b = pb & 255;

    short8 afr[2][2];
#pragma unroll
    for (int kc = 0; kc < 2; ++kc) {
        afr[0][kc] = *(const short8*)&depth_c[(size_t)(b * 2 + kc) * plane + poff + q * 8];
        afr[1][kc] = *(const short8*)&guide_c[(size_t)(b * 2 + kc) * plane + poff + q * 8];
    }

    const ushort* bbase = bufB + (size_t)(b * 2) * plane;
#pragma unroll
    for (int i = 0; i < 7; ++i) {
        int wofs = i * 4096 + (wv << 10);
        int ofs  = wofs + (lane << 4);
        if (ofs < 25344) {
            int seg = ofs / 4224;
            int within = ofs - seg * 4224;
            int cc2 = seg / 3, r = seg - cc2 * 3;
            const ushort* gsrc = bbase + (size_t)cc2 * plane
                               + ((size_t)(y0 + r) * 258 + x0b) * 32 + (within >> 1);
            gload_lds16(gsrc, (char*)stage + wofs);
        }
    }
    __syncthreads();

    floatx4 acc[2][4];
#pragma unroll
    for (int br = 0; br < 2; ++br)
#pragma unroll
        for (int nt = 0; nt < 4; ++nt) acc[br][nt] = (floatx4){0.f, 0.f, 0.f, 0.f};
#pragma unroll
    for (int nt = 0; nt < 4; ++nt)
#pragma unroll
        for (int kc = 0; kc < 2; ++kc) {
            short8 bD = *(const short8*)&w1d[(size_t)((nt * 16 + ml) * 64 + kc * 32 + q * 8)];
            short8 bG = *(const short8*)&w1g[(size_t)((nt * 16 + ml) * 64 + kc * 32 + q * 8)];
            acc[0][nt] = __builtin_amdgcn_mfma_f32_16x16x32_bf16(afr[0][kc], bD, acc[0][nt], 0, 0, 0);
            acc[1][nt] = __builtin_amdgcn_mfma_f32_16x16x32_bf16(afr[1][kc], bG, acc[1][nt], 0, 0, 0);
        }

    int colb = (wv << 4) + ml;
    floatx4 dw[4];
#pragma unroll
    for (int u = 0; u < 4; ++u) dw[u] = (floatx4){0.f, 0.f, 0.f, 0.f};
#pragma unroll
    for (int t = 0; t < 9; ++t) {
        int dy2 = t / 3, dx2 = t - 3 * dy2;
        short8 a0 = *(const short8*)&stage[(size_t)(dy2 * 66 + colb + dx2) * 32 + q * 8];
        short8 b3 = *(const short8*)&wt3[(size_t)(t * 512 + ml * 32 + q * 8)];
        dw[t & 3] = __builtin_amdgcn_mfma_f32_16x16x32_bf16(a0, b3, dw[t & 3], 0, 0, 0);
    }
#pragma unroll
    for (int t = 0; t < 9; ++t) {
        int dy2 = t / 3, dx2 = t - 3 * dy2;
        short8 a1 = *(const short8*)&stage[(size_t)((3 + dy2) * 66 + colb + dx2) * 32 + q * 8];
        short8 b3 = *(const short8*)&wt3[(size_t)((9 + t) * 512 + ml * 32 + q * 8)];
        dw[t & 3] = __builtin_amdgcn_mfma_f32_16x16x32_bf16(a1, b3, dw[t & 3], 0, 0, 0);
    }
    floatx4 dwm = (dw[0] + dw[1]) + (dw[2] + dw[3]);
    if (ml == 0) {
#pragma unroll
        for (int e = 0; e < 4; ++e) wmv[wv][q * 4 + e] = dwm[e];
    }

#pragma unroll
    for (int br = 0; br < 2; ++br) {
        const float* b1 = br ? b1g : b1d;
        ushort* h = hid[br][wv];
#pragma unroll
        for (int nt = 0; nt < 4; ++nt) {
            float bs = b1[nt * 16 + ml];
#pragma unroll
            for (int e = 0; e < 4; ++e) {
                float v = acc[br][nt][e] + bs;
                v = fmaxf(v, 0.f);
                h[(q * 4 + e) * 72 + nt * 16 + ml] = f2b(v);
            }
        }
    }

    floatx4 d2[2];
    d2[0] = (floatx4){0.f, 0.f, 0.f, 0.f};
    d2[1] = (floatx4){0.f, 0.f, 0.f, 0.f};
#pragma unroll
    for (int kc = 0; kc < 2; ++kc) {
        short8 a2d = *(const short8*)&w2d[(size_t)(ml * 64 + kc * 32 + q * 8)];
        short8 a2g = *(const short8*)&w2g[(size_t)(ml * 64 + kc * 32 + q * 8)];
        short8 hfd = *(const short8*)&hid[0][wv][ml * 72 + kc * 32 + q * 8];
        short8 hfg = *(const short8*)&hid[1][wv][ml * 72 + kc * 32 + q * 8];
        d2[0] = __builtin_amdgcn_mfma_f32_16x16x32_bf16(a2d, hfd, d2[0], 0, 0, 0);
        d2[1] = __builtin_amdgcn_mfma_f32_16x16x32_bf16(a2g, hfg, d2[1], 0, 0, 0);
    }

    float wm = wmv[wv][ml] + wn_b3[0];

    float sm[2][4];
#pragma unroll
    for (int br = 0; br < 2; ++br) {
        const float* b2 = br ? b2g : b2d;
        float lg[4];
#pragma unroll
        for (int e = 0; e < 4; ++e) {
            int j = q * 4 + e;
            lg[e] = (j < 9) ? (d2[br][e] + b2[j]) : -1e30f;
        }
        float m = fmaxf(fmaxf(lg[0], lg[1]), fmaxf(lg[2], lg[3]));
        m = fmaxf(m, __shfl_xor(m, 16));
        m = fmaxf(m, __shfl_xor(m, 32));
        float s = 0.f;
#pragma unroll
        for (int e = 0; e < 4; ++e) { lg[e] = __expf(lg[e] - m); s += lg[e]; }
        s += __shfl_xor(s, 16);
        s += __shfl_xor(s, 32);
        float inv = 1.f / s;
#pragma unroll
        for (int e = 0; e < 4; ++e) sm[br][e] = lg[e] * inv;
    }

    float inv_av = 1.f / (aff[0] + 1e-8f);
    float f[4];
    float s = 0.f;
#pragma unroll
    for (int e = 0; e < 4; ++e) {
        float v = wm * sm[0][e] + (1.f - wm) * sm[1][e];
        v = fast_tanh(v) * inv_av;
        f[e] = v;
        s += fabsf(v);
    }
    s += __shfl_xor(s, 16);
    s += __shfl_xor(s, 32);
    float ksum = s + 1e-4f;
    if (ksum < 1.f) ksum = 1.f;
    float invk = 1.f / ksum;
#pragma unroll
    for (int e = 0; e < 4; ++e) {
        int j = q * 4 + e;
        if (j < 9)
            fuse_out[((size_t)b * 9 + j) * HW2 + rem0 + ml] = f[e] * invk;
    }
}

// ===========================================================================
// Dispatch 5: rb3 standalone (bf16 out). grid (8,16,2).
// ===========================================================================
__global__ __launch_bounds__(256, 2)
void conv_single(const ushort* __restrict__ inA, const ushort* __restrict__ wt,
                 const float* __restrict__ bias, const ushort* __restrict__ skip,
                 ushort* __restrict__ outc) {
    conv_body<2, 2, false, true, false>(inA, nullptr, wt, bias, skip, outc,
                                        128, 128, blockIdx.z,
                                        blockIdx.x, blockIdx.y, threadIdx.x);
}

// ===========================================================================
// Dispatch 6: fused bilinear-upsample + 9-tap dilated gather.
// R10: both cc-chunks of a batch per thread -- coef[4][4] and the 9 fuse
// reads (identical for cc=0,1) computed ONCE instead of twice. grid (256,2).
// ===========================================================================
__global__ __launch_bounds__(256)
void fuse_apply_up(const float* __restrict__ fuse, const ushort* __restrict__ r2c,
                   float* __restrict__ out) {
    int p = blockIdx.x * 256 + threadIdx.x;
    int b = blockIdx.y;                     // batch 0..1
    int y = p >> 8, x = p & 255;

    int my = y >> 1, mx = x >> 1;
    float wyA = (y & 1) ? 0.75f : 0.25f;  float wyB = 1.f - wyA;
    float wxA = (x & 1) ? 0.75f : 0.25f;  float wxB = 1.f - wxA;
    int R0y = my + ((y & 1) ? 0 : -1) - 1;
    int R0x = mx + ((x & 1) ? 0 : -1) - 1;

    const float* f = fuse + (size_t)b * 9 * HW2 + p;
    float coef[4][4];
#pragma unroll
    for (int k = 0; k < 4; ++k)
#pragma unroll
        for (int l = 0; l < 4; ++l) coef[k][l] = 0.f;

#pragma unroll
    for (int ty = 0; ty < 3; ++ty) {
        int yp = y + (ty - 1) * 2;
        if (yp < 0 || yp > 255) continue;
#pragma unroll
        for (int tx = 0; tx < 3; ++tx) {
            int xp = x + (tx - 1) * 2;
            if (xp < 0 || xp > 255) continue;
            float fv = f[(size_t)(ty * 3 + tx) * HW2];
            coef[ty][tx]         += fv * wyA * wxA;
            coef[ty][tx + 1]     += fv * wyA * wxB;
            coef[ty + 1][tx]     += fv * wyB * wxA;
            coef[ty + 1][tx + 1] += fv * wyB * wxB;
        }
    }

    // clamped tap rows/cols shared by both cc-chunks
    int ryv[4], rxv[4];
#pragma unroll
    for (int k = 0; k < 4; ++k) {
        int ry = R0y + k; ryv[k] = ry < 0 ? 0 : (ry > 127 ? 127 : ry);
        int rx = R0x + k; rxv[k] = rx < 0 ? 0 : (rx > 127 ? 127 : rx);
    }

    for (int cc = 0; cc < 2; ++cc) {
        const ushort* base = r2c + (size_t)(b * 2 + cc) * 130 * 130 * 32;
        float acc[32];
#pragma unroll
        for (int c = 0; c < 32; ++c) acc[c] = 0.f;
#pragma unroll
        for (int k = 0; k < 4; ++k) {
#pragma unroll
            for (int l = 0; l < 4; ++l) {
                float cf = coef[k][l];
                const ushort* u = base + ((size_t)(ryv[k] + 1) * 130 + (rxv[l] + 1)) * 32;
#pragma unroll
                for (int c = 0; c < 32; ++c) acc[c] = fmaf(cf, b2f(u[c]), acc[c]);
            }
        }
        float* ob = out + ((size_t)(b * 64 + cc * 32)) * HW2 + p;
#pragma unroll
        for (int c = 0; c < 32; ++c) ob[(size_t)c * HW2] = acc[c];
    }
}

// ---------------------------------------------------------------------------
extern "C" void kernel_launch(void* const* d_in, const int* in_sizes, int n_in,
                              void* d_out, int out_size, void* d_ws, size_t ws_size,
                              hipStream_t stream) {
    const float* depth  = (const float*)d_in[0];
    const float* guide  = (const float*)d_in[1];
    const float* inputs = (const float*)d_in[2];
    const float* dk_w1  = (const float*)d_in[3];
    const float* dk_b1  = (const float*)d_in[4];
    const float* dk_w2  = (const float*)d_in[5];
    const float* dk_b2  = (const float*)d_in[6];
    const float* gk_w1  = (const float*)d_in[7];
    const float* gk_b1  = (const float*)d_in[8];
    const float* gk_w2  = (const float*)d_in[9];
    const float* gk_b2  = (const float*)d_in[10];
    const float* wn_w1  = (const float*)d_in[11];
    const float* wn_b1  = (const float*)d_in[12];
    const float* wn_w2  = (const float*)d_in[13];
    const float* wn_b2  = (const float*)d_in[14];
    const float* wn_w3  = (const float*)d_in[15];
    const float* wn_b3  = (const float*)d_in[16];
    const float* rb_w   = (const float*)d_in[17];
    const float* rb_b   = (const float*)d_in[18];
    const float* aff    = (const float*)d_in[19];
    float* out = (float*)d_out;

    float* ws = (float*)d_ws;
    size_t off = 0;
    const size_t CH256 = 4260096;
    const size_t CH128 = 1081600;
    ushort* depth_c = (ushort*)(ws + off); off += CH256;
    ushort* guide_c = (ushort*)(ws + off); off += CH256;
    ushort* bufA    = (ushort*)(ws + off); off += CH256;
    ushort* bufB    = (ushort*)(ws + off); off += CH256;
    ushort* inp_c   = (ushort*)(ws + off); off += CH128;
    ushort* r0      = (ushort*)(ws + off); off += CH128;
    ushort* r1      = (ushort*)(ws + off); off += CH128;
    ushort* r2      = (ushort*)(ws + off); off += CH128;
    float* fuse     = ws + off; off += 1179648;
    ushort* wt_wn1  = (ushort*)(ws + off); off += 36864;
    ushort* wt_wn2  = (ushort*)(ws + off); off += 18432;
    ushort* wt_rb   = (ushort*)(ws + off); off += 73728;
    ushort* w1d_b   = (ushort*)(ws + off); off += 2048;
    ushort* w1g_b   = (ushort*)(ws + off); off += 2048;
    ushort* w2d_b   = (ushort*)(ws + off); off += 512;
    ushort* w2g_b   = (ushort*)(ws + off); off += 512;
    ushort* wt3_b   = (ushort*)(ws + off); off += 4608;

    // D1: all prep
    prep_all<<<3183, 256, 0, stream>>>(
        depth, guide, inputs, wn_w1, wn_w2, rb_w, dk_w1, gk_w1, dk_w2, gk_w2,
        wn_w3, depth_c, inp_c, wt_wn1, wt_wn2, wt_rb,
        w1d_b, w1g_b, w2d_b, w2g_b, wt3_b, bufA, r0);

    // D2: conv1 || rb0
    conv_pairA<<<dim3(16, 16, 3), 256, 0, stream>>>(
        depth_c, guide_c, wt_wn1, wn_b1, bufA,
        inp_c, wt_rb + 0 * 36864, rb_b + 0 * 64, r0);

    // D3: conv2 || rb1
    conv_pairB<<<dim3(16, 16, 3), 256, 0, stream>>>(
        bufA, wt_wn2, wn_b2, bufB,
        r0, wt_rb + 1 * 36864, rb_b + 1 * 64, inp_c, r1);

    // D4: fuse || rb2
    fuse_rb2<<<2304, 256, 0, stream>>>(
        depth_c, guide_c, bufB, wt3_b, wn_b3,
        w1d_b, dk_b1, w2d_b, dk_b2, w1g_b, gk_b1, w2g_b, gk_b2,
        aff, fuse,
        r1, wt_rb + 2 * 36864, rb_b + 2 * 64, r0);

    // D5: rb3
    conv_single<<<dim3(8, 16, 2), 256, 0, stream>>>(
        r0, wt_rb + 3 * 36864, rb_b + 3 * 64, r1, r2);

    // D6: fused upsample + gather (both cc per thread)
    fuse_apply_up<<<dim3(256, 2), 256, 0, stream>>>(fuse, r2, out);
}